// Round 4
// baseline (15.325 us; speedup 1.0000x reference)
//
#include <hip/hip_runtime.h>
#include <math.h>

#define NG 512
#define NV 76800
#define FD 32
#define CAP 128
// grid 80x80x12 voxels, tiles 8x8x4 -> 10x10x3 = 300 tiles

__global__ __launch_bounds__(256) void voxelize_kernel(
    const float* __restrict__ means, const float* __restrict__ opac,
    const float* __restrict__ cov, const float* __restrict__ feats,
    float* __restrict__ out)
{
    __shared__ float4 gp[CAP + 1];      // mx,my,mz,r2
    __shared__ float4 gq[CAP + 1];      // i00,i01,i02,i11
    __shared__ float4 gt[CAP + 1];      // i12,i22,op,-
    __shared__ float  gf[CAP + 1][FD];  // staged feature rows
    __shared__ int    s_n[CAP];
    __shared__ int    s_cnt;

    const int tid  = threadIdx.x;
    const int wv   = tid >> 6;
    const int lane = tid & 63;

    const int b   = blockIdx.x;
    const int tiz = b % 3;
    const int tiy = (b / 3) % 10;
    const int tix = b / 30;

    // tile voxel-center AABB (world units)
    const float xlo = (tix * 8 + 0.5f) * 0.5f - 20.f, xhi = xlo + 3.5f;
    const float ylo = (tiy * 8 + 0.5f) * 0.5f - 20.f, yhi = ylo + 3.5f;
    const float zlo = (tiz * 4 + 0.5f) * 0.5f -  2.f, zhi = zlo + 1.5f;

    if (tid == 0) s_cnt = 0;
    __syncthreads();

    // ---- phase 1: gate 512 gaussians, compact survivors (block-wide list)
    #pragma unroll
    for (int r = 0; r < 2; ++r) {
        const int n = wv * 128 + r * 64 + lane;
        const float a = cov[n*9+0], bb = cov[n*9+1], c = cov[n*9+2];
        const float d = cov[n*9+4], e  = cov[n*9+5], f = cov[n*9+8];
        const float sx = sqrtf(a), sy = sqrtf(d), sz = sqrtf(f);
        const float mx = means[n*3+0], my = means[n*3+1], mz = means[n*3+2];
        const float op = opac[n];
        const bool keep =
            (mx + 3.f*sx > -20.f) && (my + 3.f*sy > -20.f) && (mz + 3.f*sz > -2.f) &&
            (mx - 3.f*sx <  20.f) && (my - 3.f*sy <  20.f) && (mz - 3.f*sz <  4.4f) &&
            (op > 1e-4f);
        const float smax = fmaxf(sx, fmaxf(sy, sz));
        const float r2 = 9.f * smax * smax;
        const float cx = fminf(fmaxf(mx, xlo), xhi) - mx;
        const float cy = fminf(fmaxf(my, ylo), yhi) - my;
        const float cz = fminf(fmaxf(mz, zlo), zhi) - mz;
        const float d2t = cx*cx + cy*cy + cz*cz;
        const bool pred = keep && (d2t < r2);

        const unsigned long long m = __ballot(pred);
        int wofs = 0;
        if (lane == 0) wofs = atomicAdd(&s_cnt, (int)__popcll(m));
        wofs = __shfl(wofs, 0);
        const int pos = wofs + (int)__popcll(m & ((1ull << lane) - 1ull));
        if (pred && pos < CAP) {
            const float det = a*(d*f - e*e) - bb*(bb*f - c*e) + c*(bb*e - c*d);
            const float id = 1.f / det;
            gp[pos] = make_float4(mx, my, mz, r2);
            gq[pos] = make_float4((d*f - e*e) * id,   // i00
                                  (c*e - bb*f) * id,  // i01
                                  (bb*e - c*d) * id,  // i02
                                  (a*f - c*c) * id);  // i11
            gt[pos] = make_float4((bb*c - a*e) * id,  // i12
                                  (a*d - bb*bb) * id, // i22
                                  op, 0.f);
            s_n[pos] = n;
        }
    }
    __syncthreads();
    const int ks  = (s_cnt < CAP) ? s_cnt : CAP;
    const int ks2 = (ks + 1) & ~1;   // even-padded trip count

    // pad record: gate always false (r2=-1), finite maha (inv=0), op=0
    if (tid == 0 && ks2 > ks) {
        gp[ks] = make_float4(1e9f, 1e9f, 1e9f, -1.f);
        gq[ks] = make_float4(0.f, 0.f, 0.f, 0.f);
        gt[ks] = make_float4(0.f, 0.f, 0.f, 0.f);
    }

    // ---- phase 1.5: stage survivor feature rows into LDS (zero the pad row)
    for (int it = tid; it < ks2 * 8; it += 256) {
        const int s = it >> 3, j = it & 7;
        ((float4*)gf[s])[j] = (s < ks)
            ? ((const float4*)(feats + (size_t)s_n[s] * FD))[j]
            : make_float4(0.f, 0.f, 0.f, 0.f);
    }
    __syncthreads();

    // ---- phase 2: branchless, 2x-unrolled per-voxel accumulation
    const int lz = tid & 3;
    const int ly = (tid >> 2) & 7;
    const int lx = tid >> 5;
    const int ix = tix * 8 + lx;
    const int iy = tiy * 8 + ly;
    const int iz = tiz * 4 + lz;
    const float x = (ix + 0.5f) * 0.5f - 20.f;
    const float y = (iy + 0.5f) * 0.5f - 20.f;
    const float z = (iz + 0.5f) * 0.5f -  2.f;

    float dens = 0.f;
    float4 acc[8];
    #pragma unroll
    for (int j = 0; j < 8; ++j) acc[j] = make_float4(0.f, 0.f, 0.f, 0.f);

    for (int i = 0; i < ks2; i += 2) {
        const float4 p0 = gp[i],   q0 = gq[i],   t0 = gt[i];
        const float4 p1 = gp[i+1], q1 = gq[i+1], t1 = gt[i+1];

        const float dx0 = p0.x - x, dy0 = p0.y - y, dz0 = p0.z - z;
        const float dx1 = p1.x - x, dy1 = p1.y - y, dz1 = p1.z - z;
        const float d20 = dx0*dx0 + dy0*dy0 + dz0*dz0;
        const float d21 = dx1*dx1 + dy1*dy1 + dz1*dz1;
        const float maha0 = q0.x*dx0*dx0 + q0.w*dy0*dy0 + t0.y*dz0*dz0
                          + 2.f*(q0.y*dx0*dy0 + q0.z*dx0*dz0 + t0.x*dy0*dz0);
        const float maha1 = q1.x*dx1*dx1 + q1.w*dy1*dy1 + t1.y*dz1*dz1
                          + 2.f*(q1.y*dx1*dy1 + q1.z*dx1*dz1 + t1.x*dy1*dz1);
        float w0 = t0.z * __expf(-0.5f * maha0);
        float w1 = t1.z * __expf(-0.5f * maha1);
        w0 = (d20 < p0.w) ? w0 : 0.f;   // select AFTER exp: no 0*inf
        w1 = (d21 < p1.w) ? w1 : 0.f;
        dens += w0 + w1;

        const float4* f0 = (const float4*)gf[i];
        const float4* f1 = (const float4*)gf[i+1];
        #pragma unroll
        for (int j = 0; j < 8; ++j) {
            const float4 a0 = f0[j];
            const float4 a1 = f1[j];
            acc[j].x += w0*a0.x + w1*a1.x;
            acc[j].y += w0*a0.y + w1*a1.y;
            acc[j].z += w0*a0.z + w1*a1.z;
            acc[j].w += w0*a0.w + w1*a1.w;
        }
    }

    const int v = (ix * 80 + iy) * 12 + iz;
    out[v] = dens;
    const float inv = 1.f / fmaxf(dens, 1e-6f);
    float4* fo = (float4*)(out + NV + (size_t)v * FD);
    #pragma unroll
    for (int j = 0; j < 8; ++j) {
        float4 rr;
        rr.x = acc[j].x * inv; rr.y = acc[j].y * inv;
        rr.z = acc[j].z * inv; rr.w = acc[j].w * inv;
        fo[j] = rr;
    }
}

extern "C" void kernel_launch(void* const* d_in, const int* in_sizes, int n_in,
                              void* d_out, int out_size, void* d_ws, size_t ws_size,
                              hipStream_t stream) {
    const float* means = (const float*)d_in[0];
    const float* opac  = (const float*)d_in[1];
    const float* cov   = (const float*)d_in[2];
    const float* feats = (const float*)d_in[3];
    float* out = (float*)d_out;
    voxelize_kernel<<<300, 256, 0, stream>>>(means, opac, cov, feats, out);
}

// Round 5
// 15.287 us; speedup vs baseline: 1.0025x; 1.0025x over previous
//
#include <hip/hip_runtime.h>
#include <math.h>

#define NG 512
#define NV 76800
#define FD 32
#define CAP 160
// grid 80x80x12 voxels; tiles 8x8x12 (full z column) -> 10x10 = 100 blocks x 768 threads

__global__ __launch_bounds__(768) void voxelize_kernel(
    const float* __restrict__ means, const float* __restrict__ opac,
    const float* __restrict__ cov, const float* __restrict__ feats,
    float* __restrict__ out)
{
    __shared__ float4 gp[CAP];          // mx,my,mz,r2
    __shared__ float4 gq[CAP];          // i00,i01,i02,i11
    __shared__ float4 gt[CAP];          // i12,i22,op,-
    __shared__ float  gf[CAP][FD];      // staged feature rows
    __shared__ int    s_n[CAP];
    __shared__ int    s_cnt;

    const int tid  = threadIdx.x;
    const int lane = tid & 63;

    const int b   = blockIdx.x;
    const int tiy = b % 10;
    const int tix = b / 10;

    // tile voxel-center AABB (world units)
    const float xlo = (tix * 8 + 0.5f) * 0.5f - 20.f, xhi = xlo + 3.5f;
    const float ylo = (tiy * 8 + 0.5f) * 0.5f - 20.f, yhi = ylo + 3.5f;
    const float zlo = 0.5f * 0.5f - 2.f,               zhi = zlo + 5.5f;

    if (tid == 0) s_cnt = 0;
    __syncthreads();

    // ---- phase 1: gate 512 gaussians (threads 0..511, one each), compact survivors
    if (tid < NG) {
        const int n = tid;
        const float a = cov[n*9+0], bb = cov[n*9+1], c = cov[n*9+2];
        const float d = cov[n*9+4], e  = cov[n*9+5], f = cov[n*9+8];
        const float sx = sqrtf(a), sy = sqrtf(d), sz = sqrtf(f);
        const float mx = means[n*3+0], my = means[n*3+1], mz = means[n*3+2];
        const float op = opac[n];
        const bool keep =
            (mx + 3.f*sx > -20.f) && (my + 3.f*sy > -20.f) && (mz + 3.f*sz > -2.f) &&
            (mx - 3.f*sx <  20.f) && (my - 3.f*sy <  20.f) && (mz - 3.f*sz <  4.4f) &&
            (op > 1e-4f);
        const float smax = fmaxf(sx, fmaxf(sy, sz));
        const float r2 = 9.f * smax * smax;
        // distance from gaussian center to tile voxel-center AABB
        const float cx = fminf(fmaxf(mx, xlo), xhi) - mx;
        const float cy = fminf(fmaxf(my, ylo), yhi) - my;
        const float cz = fminf(fmaxf(mz, zlo), zhi) - mz;
        const float d2t = cx*cx + cy*cy + cz*cz;
        const bool pred = keep && (d2t < r2);

        const unsigned long long m = __ballot(pred);
        int wofs = 0;
        if (lane == 0) wofs = atomicAdd(&s_cnt, (int)__popcll(m));
        wofs = __shfl(wofs, 0);
        const int pos = wofs + (int)__popcll(m & ((1ull << lane) - 1ull));
        if (pred && pos < CAP) {
            const float det = a*(d*f - e*e) - bb*(bb*f - c*e) + c*(bb*e - c*d);
            const float id = 1.f / det;
            gp[pos] = make_float4(mx, my, mz, r2);
            gq[pos] = make_float4((d*f - e*e) * id,   // i00
                                  (c*e - bb*f) * id,  // i01
                                  (bb*e - c*d) * id,  // i02
                                  (a*f - c*c) * id);  // i11
            gt[pos] = make_float4((bb*c - a*e) * id,  // i12
                                  (a*d - bb*bb) * id, // i22
                                  op, 0.f);
            s_n[pos] = n;
        }
    }
    __syncthreads();
    const int ks = (s_cnt < CAP) ? s_cnt : CAP;

    // ---- phase 1.5: stage survivor feature rows into LDS (coalesced float4)
    for (int it = tid; it < ks * 8; it += 768) {
        const int s = it >> 3, j = it & 7;
        ((float4*)gf[s])[j] = ((const float4*)(feats + (size_t)s_n[s] * FD))[j];
    }
    __syncthreads();

    // ---- phase 2: per-voxel accumulation over compacted list (branchy: best so far)
    const int lz = tid % 12;
    const int lyx = tid / 12;
    const int ly = lyx % 8;
    const int lx = lyx / 8;
    const int ix = tix * 8 + lx;
    const int iy = tiy * 8 + ly;
    const int iz = lz;
    const float x = (ix + 0.5f) * 0.5f - 20.f;
    const float y = (iy + 0.5f) * 0.5f - 20.f;
    const float z = (iz + 0.5f) * 0.5f -  2.f;

    float dens = 0.f;
    float4 acc[8];
    #pragma unroll
    for (int j = 0; j < 8; ++j) acc[j] = make_float4(0.f, 0.f, 0.f, 0.f);

    for (int i = 0; i < ks; ++i) {
        const float4 p = gp[i];
        const float dx = p.x - x, dy = p.y - y, dz = p.z - z;
        const float d2 = dx*dx + dy*dy + dz*dz;
        if (d2 < p.w) {
            const float4 q = gq[i];
            const float4 t = gt[i];
            const float maha = q.x*dx*dx + q.w*dy*dy + t.y*dz*dz
                             + 2.f*(q.y*dx*dy + q.z*dx*dz + t.x*dy*dz);
            const float w = t.z * __expf(-0.5f * maha);
            dens += w;
            const float4* fp = (const float4*)gf[i];
            #pragma unroll
            for (int j = 0; j < 8; ++j) {
                const float4 f4 = fp[j];
                acc[j].x += w * f4.x; acc[j].y += w * f4.y;
                acc[j].z += w * f4.z; acc[j].w += w * f4.w;
            }
        }
    }

    const int v = (ix * 80 + iy) * 12 + iz;
    out[v] = dens;
    const float inv = 1.f / fmaxf(dens, 1e-6f);
    float4* fo = (float4*)(out + NV + (size_t)v * FD);
    #pragma unroll
    for (int j = 0; j < 8; ++j) {
        float4 rr;
        rr.x = acc[j].x * inv; rr.y = acc[j].y * inv;
        rr.z = acc[j].z * inv; rr.w = acc[j].w * inv;
        fo[j] = rr;
    }
}

extern "C" void kernel_launch(void* const* d_in, const int* in_sizes, int n_in,
                              void* d_out, int out_size, void* d_ws, size_t ws_size,
                              hipStream_t stream) {
    const float* means = (const float*)d_in[0];
    const float* opac  = (const float*)d_in[1];
    const float* cov   = (const float*)d_in[2];
    const float* feats = (const float*)d_in[3];
    float* out = (float*)d_out;
    voxelize_kernel<<<100, 768, 0, stream>>>(means, opac, cov, feats, out);
}

// Round 6
// 13.917 us; speedup vs baseline: 1.1012x; 1.0984x over previous
//
#include <hip/hip_runtime.h>
#include <math.h>

#define NG 512
#define NV 76800
#define FD 32
#define CAP 64
// voxel grid 80x80x12; tiles 8x8x6 -> 10x10x2 = 200 blocks
// block = 768 threads = 12 waves (3/SIMD): 2 survivor-slices x 384 voxels

__global__ __launch_bounds__(768, 3) void voxelize_kernel(
    const float* __restrict__ means, const float* __restrict__ opac,
    const float* __restrict__ cov, const float* __restrict__ feats,
    float* __restrict__ out)
{
    // LDS pool: phase A = records (~12 KB), phase B = partials [33][384] (50.7 KB)
    __shared__ float pool[33 * 384];
    __shared__ int   s_n[CAP];
    __shared__ int   s_cnt;

    float4* gp = (float4*)pool;          // [CAP+4] mx,my,mz,r2
    float4* gq = gp + (CAP + 4);         // [CAP+4] i00,i01,i02,i11
    float4* gt = gq + (CAP + 4);         // [CAP+4] i12,i22,op,-
    float*  gf = (float*)(gt + (CAP + 4)); // [CAP+4][FD]

    const int tid  = threadIdx.x;
    const int lane = tid & 63;

    const int b   = blockIdx.x;
    const int tiz = b % 2;
    const int tiy = (b / 2) % 10;
    const int tix = b / 20;

    // tile voxel-center AABB (world units)
    const float xlo = (tix * 8 + 0.5f) * 0.5f - 20.f, xhi = xlo + 3.5f;
    const float ylo = (tiy * 8 + 0.5f) * 0.5f - 20.f, yhi = ylo + 3.5f;
    const float zlo = (tiz * 6 + 0.5f) * 0.5f -  2.f, zhi = zlo + 2.5f;

    if (tid == 0) s_cnt = 0;
    __syncthreads();

    // ---- phase 1: gate 512 gaussians (threads 0..511), compact survivors
    if (tid < NG) {
        const int n = tid;
        const float a = cov[n*9+0], bb = cov[n*9+1], c = cov[n*9+2];
        const float d = cov[n*9+4], e  = cov[n*9+5], f = cov[n*9+8];
        const float sx = sqrtf(a), sy = sqrtf(d), sz = sqrtf(f);
        const float mx = means[n*3+0], my = means[n*3+1], mz = means[n*3+2];
        const float op = opac[n];
        const bool keep =
            (mx + 3.f*sx > -20.f) && (my + 3.f*sy > -20.f) && (mz + 3.f*sz > -2.f) &&
            (mx - 3.f*sx <  20.f) && (my - 3.f*sy <  20.f) && (mz - 3.f*sz <  4.4f) &&
            (op > 1e-4f);
        const float smax = fmaxf(sx, fmaxf(sy, sz));
        const float r2 = 9.f * smax * smax;
        const float cx = fminf(fmaxf(mx, xlo), xhi) - mx;
        const float cy = fminf(fmaxf(my, ylo), yhi) - my;
        const float cz = fminf(fmaxf(mz, zlo), zhi) - mz;
        const float d2t = cx*cx + cy*cy + cz*cz;
        const bool pred = keep && (d2t < r2);

        const unsigned long long m = __ballot(pred);
        int wofs = 0;
        if (lane == 0) wofs = atomicAdd(&s_cnt, (int)__popcll(m));
        wofs = __shfl(wofs, 0);
        const int pos = wofs + (int)__popcll(m & ((1ull << lane) - 1ull));
        if (pred && pos < CAP) {
            const float det = a*(d*f - e*e) - bb*(bb*f - c*e) + c*(bb*e - c*d);
            const float id = 1.f / det;
            gp[pos] = make_float4(mx, my, mz, r2);
            gq[pos] = make_float4((d*f - e*e) * id,
                                  (c*e - bb*f) * id,
                                  (bb*e - c*d) * id,
                                  (a*f - c*c) * id);
            gt[pos] = make_float4((bb*c - a*e) * id,
                                  (a*d - bb*bb) * id,
                                  op, 0.f);
            s_n[pos] = n;
        }
    }
    __syncthreads();
    const int ks = (s_cnt < CAP) ? s_cnt : CAP;

    // ---- pad 4 dummy records after the list (prefetch reads them branch-free)
    if (tid < 4) {
        gp[ks + tid] = make_float4(1e9f, 1e9f, 1e9f, -1.f);
        gq[ks + tid] = make_float4(0.f, 0.f, 0.f, 0.f);
        gt[ks + tid] = make_float4(0.f, 0.f, 0.f, 0.f);
    }
    // zero the 4 dummy feature rows (128 floats = 32 float4)
    if (tid < 32) ((float4*)(gf + ks * FD))[tid] = make_float4(0.f, 0.f, 0.f, 0.f);

    // ---- phase 1.5: stage survivor feature rows into LDS
    for (int it = tid; it < ks * 8; it += 768) {
        const int s = it >> 3, j = it & 7;
        ((float4*)(gf + s * FD))[j] = ((const float4*)(feats + (size_t)s_n[s] * FD))[j];
    }
    __syncthreads();

    // ---- phase 2: branchless, sliced (2 slices), 1-ahead prefetched
    const int sl = tid / 384;           // survivor slice 0/1 (wave-uniform: 6 waves each)
    const int u  = tid - sl * 384;      // voxel index within tile
    const int lz = u % 6;
    const int ly = (u / 6) % 8;
    const int lx = u / 48;
    const int ix = tix * 8 + lx;
    const int iy = tiy * 8 + ly;
    const int iz = tiz * 6 + lz;
    const float x = (ix + 0.5f) * 0.5f - 20.f;
    const float y = (iy + 0.5f) * 0.5f - 20.f;
    const float z = (iz + 0.5f) * 0.5f -  2.f;

    float dens = 0.f;
    float4 acc[8];
    #pragma unroll
    for (int j = 0; j < 8; ++j) acc[j] = make_float4(0.f, 0.f, 0.f, 0.f);

    // prologue: load slice's first record (dummy-safe)
    float4 p = gp[sl], q = gq[sl], t = gt[sl];
    float4 f[8];
    #pragma unroll
    for (int j = 0; j < 8; ++j) f[j] = ((float4*)(gf + sl * FD))[j];

    for (int i = sl; i < ks; i += 2) {
        const int ip = i + 2;           // <= ks+1: dummy records exist
        const float4 pn = gp[ip], qn = gq[ip], tn = gt[ip];
        float4 fn[8];
        #pragma unroll
        for (int j = 0; j < 8; ++j) fn[j] = ((float4*)(gf + ip * FD))[j];

        const float dx = p.x - x, dy = p.y - y, dz = p.z - z;
        const float d2 = dx*dx + dy*dy + dz*dz;
        const float maha = q.x*dx*dx + q.w*dy*dy + t.y*dz*dz
                         + 2.f*(q.y*dx*dy + q.z*dx*dz + t.x*dy*dz);
        float w = t.z * __expf(-0.5f * maha);
        w = (d2 < p.w) ? w : 0.f;       // select after exp: no 0*inf
        dens += w;
        #pragma unroll
        for (int j = 0; j < 8; ++j) {
            acc[j].x += w * f[j].x; acc[j].y += w * f[j].y;
            acc[j].z += w * f[j].z; acc[j].w += w * f[j].w;
        }
        p = pn; q = qn; t = tn;
        #pragma unroll
        for (int j = 0; j < 8; ++j) f[j] = fn[j];
    }

    // ---- phase 3: cross-slice reduction via LDS partials [33][384]
    __syncthreads();                    // records dead; pool reusable
    if (sl == 1) {
        pool[u] = dens;
        #pragma unroll
        for (int j = 0; j < 8; ++j) {
            pool[(1 + j*4 + 0) * 384 + u] = acc[j].x;
            pool[(1 + j*4 + 1) * 384 + u] = acc[j].y;
            pool[(1 + j*4 + 2) * 384 + u] = acc[j].z;
            pool[(1 + j*4 + 3) * 384 + u] = acc[j].w;
        }
    }
    __syncthreads();
    if (sl == 0) {
        dens += pool[u];
        #pragma unroll
        for (int j = 0; j < 8; ++j) {
            acc[j].x += pool[(1 + j*4 + 0) * 384 + u];
            acc[j].y += pool[(1 + j*4 + 1) * 384 + u];
            acc[j].z += pool[(1 + j*4 + 2) * 384 + u];
            acc[j].w += pool[(1 + j*4 + 3) * 384 + u];
        }
        const int v = (ix * 80 + iy) * 12 + iz;
        out[v] = dens;
        const float inv = 1.f / fmaxf(dens, 1e-6f);
        float4* fo = (float4*)(out + NV + (size_t)v * FD);
        #pragma unroll
        for (int j = 0; j < 8; ++j) {
            float4 rr;
            rr.x = acc[j].x * inv; rr.y = acc[j].y * inv;
            rr.z = acc[j].z * inv; rr.w = acc[j].w * inv;
            fo[j] = rr;
        }
    }
}

extern "C" void kernel_launch(void* const* d_in, const int* in_sizes, int n_in,
                              void* d_out, int out_size, void* d_ws, size_t ws_size,
                              hipStream_t stream) {
    const float* means = (const float*)d_in[0];
    const float* opac  = (const float*)d_in[1];
    const float* cov   = (const float*)d_in[2];
    const float* feats = (const float*)d_in[3];
    float* out = (float*)d_out;
    voxelize_kernel<<<200, 768, 0, stream>>>(means, opac, cov, feats, out);
}